// Round 4
// baseline (150.291 us; speedup 1.0000x reference)
//
#include <hip/hip_runtime.h>
#include <math.h>

#define BATCH  256
#define NQ     1000
#define HQ     500      // rows per half-block; 500*81=40500 is float4-aligned
#define NC     81
#define QC     81000
#define HQC    40500
#define TOPK   100
#define NBINS  4096
#define CAP    4096
#define CAP2   1024
#define NT     512
#define NT2    256
#define MARGIN 4096u   // bit-space sliver below a bin floor (~5e-4 rel) covering
                       // fast-vs-precise score error (~few*1e-6) with 100x slack

// Precise logistic, matching jax.nn.sigmoid (per-q factors + final candidates
// -> output scores bit-identical to the known-absmax=0 kernel).
__device__ __forceinline__ float sigmoidf(float x) {
    if (x >= 0.f) return 1.f / (1.f + expf(-x));
    float e = expf(x);
    return e / (1.f + e);
}

// Fast branch-free logistic (<=1 always; key = P*fast_sig <= P).
__device__ __forceinline__ float fast_sig(float x) {
    return __builtin_amdgcn_rcpf(1.f + __expf(-x));
}

// Wave-aggregated slot reservation: one LDS atomic per wave instead of one per
// passing lane. Return value is only meaningful for lanes with pass==true.
__device__ __forceinline__ unsigned ballot_append(unsigned* cnt, bool pass) {
    unsigned long long mask = __ballot(pass);
    unsigned base = 0;
    if (mask) {
        int lane   = (int)(threadIdx.x & 63);
        int leader = __ffsll((long long)mask) - 1;
        if (lane == leader) base = atomicAdd(cnt, (unsigned)__popcll(mask));
        base = __shfl(base, leader, 64);
        base += (unsigned)__popcll(mask & ((1ull << lane) - 1ull));
    }
    return base;
}

struct alignas(16) Smem {     // alignas: hist is zeroed via uint4 (ds_write_b128)
    float    P[HQ];       // exp(-obj)*(1-sig(unk))  — per-row upper bound
    float    Pm2[HQ];     // max(P[q], P[q+1])       — row skip bound
    float    op[HQ];      // exp(-obj)               (precise)
    float    omun[HQ];    // 1 - sig(unk)            (precise)
    float    last[HQ];    // exp(-obj)*sig(unk)      class 80 (precise)
    unsigned hist[NBINS];
    uint2    cand[CAP];   // .x = approx key bits, .y = GLOBAL flat index
    uint2    cand2[CAP2]; // .x = precise score bits, .y = GLOBAL flat index
    int      rowlist[HQ];
    unsigned nrows;
    unsigned cnt;
    unsigned cnt2;
    unsigned thr;
};
// LDS ~67.7 KB -> 2 blocks/CU co-resident (hides barrier/latency bubbles that
// dominate the 1-block/CU single-kernel variant).

// Largest bin t with |{keys in bins >= t}| >= TOPK. Wave-0 shuffle suffix scan.
__device__ unsigned scan_threshold(Smem& s, int tid) {
    __syncthreads();
    if (tid < 64) {
        unsigned c = 0;
        #pragma unroll
        for (int j = 0; j < 64; ++j) {
            int jj = (j + tid) & 63;
            c += s.hist[tid * 64 + jj];
        }
        unsigned ssum = c;
        #pragma unroll
        for (int off = 1; off < 64; off <<= 1) {
            unsigned o = __shfl_down(ssum, off, 64);
            if (tid + off < 64) ssum += o;
        }
        unsigned long long bal = __ballot(ssum >= TOPK);
        int cb = 63 - __clzll(bal);
        unsigned tb = 0;
        if (cb >= 0) {
            unsigned S_cb = __shfl(ssum, cb, 64);
            unsigned c_cb = __shfl(c, cb, 64);
            unsigned acc  = S_cb - c_cb;          // count strictly above coarse bin
            unsigned fs = s.hist[cb * 64 + tid];
            #pragma unroll
            for (int off = 1; off < 64; off <<= 1) {
                unsigned o = __shfl_down(fs, off, 64);
                if (tid + off < 64) fs += o;
            }
            unsigned long long bal2 = __ballot(acc + fs >= TOPK);
            int fb = 63 - __clzll(bal2);
            tb = (unsigned)(cb * 64 + fb);
        }
        if (tid == 0) s.thr = tb;
    }
    __syncthreads();
    return s.thr;
}

// Compact list of local rows whose bound can reach thbits.
__device__ void build_rows(Smem& s, unsigned thbits, int tid) {
    __syncthreads();
    if (tid == 0) s.nrows = 0;
    __syncthreads();
    for (int q = tid; q < HQ; q += NT) {
        bool pass = (__float_as_uint(s.Pm2[q]) >= thbits);
        unsigned p = ballot_append(&s.nrows, pass);
        if (pass) s.rowlist[p] = q;
    }
    __syncthreads();
}

// FUSED walk over owned chunks of listed rows: histogram + (key,idx) append
// for every element with key >= thbits. Local row q owns chunks
// [ceil(81q/4), ceil(81(q+1)/4)) — disjoint & complete within the half
// (half boundary at element 40500 is float4-aligned -> no cross-half spill).
__device__ void scan_fused(Smem& s, const float4* __restrict__ lg4,
                           unsigned thbits, int tid, int q0) {
    const int total = (int)s.nrows * 21;
    for (int idx = tid; idx < total; idx += NT) {
        int r  = idx / 21;
        int j  = idx - r * 21;
        int q  = s.rowlist[r];
        int e0 = NC * q;
        int i4 = ((e0 + 3) >> 2) + j;
        if (4 * i4 < e0 + NC) {
            float4 v4 = lg4[i4];
            int c = 4 * i4 - e0;
            float xs[4] = {v4.x, v4.y, v4.z, v4.w};
            #pragma unroll
            for (int k = 0; k < 4; ++k) {
                int ck = c + k, qk = q;
                if (ck >= NC) { ck -= NC; ++qk; }
                bool pass = false; unsigned u = 0;
                if (ck < 60) {                   // 60..79 invalid; 80 separate
                    float Pq = s.P[qk];
                    if (__float_as_uint(Pq) >= thbits) {  // element-level bound
                        u = __float_as_uint(Pq * fast_sig(xs[k]));
                        pass = (u >= thbits);
                    }
                }
                if (pass) atomicAdd(&s.hist[u >> 19], 1u);
                unsigned p = ballot_append(&s.cnt, pass);
                if (pass && p < CAP)
                    s.cand[p] = make_uint2(u, (unsigned)((q0 + qk) * NC + ck));
            }
        }
    }
}

// Fallback: precise collection into cand2 by row walk (rare path).
__device__ void collect_precise(Smem& s, const float4* __restrict__ lg4,
                                unsigned thbits, int tid, int q0) {
    const int total = (int)s.nrows * 21;
    for (int idx = tid; idx < total; idx += NT) {
        int r  = idx / 21;
        int j  = idx - r * 21;
        int q  = s.rowlist[r];
        int e0 = NC * q;
        int i4 = ((e0 + 3) >> 2) + j;
        if (4 * i4 < e0 + NC) {
            float4 v4 = lg4[i4];
            int c = 4 * i4 - e0;
            float xs[4] = {v4.x, v4.y, v4.z, v4.w};
            #pragma unroll
            for (int k = 0; k < 4; ++k) {
                int ck = c + k, qk = q;
                if (ck >= NC) { ck -= NC; ++qk; }
                if (ck < 60) {
                    unsigned u = __float_as_uint(s.P[qk] * fast_sig(xs[k]));
                    if (u >= thbits) {
                        float pv = (s.op[qk] * sigmoidf(xs[k])) * s.omun[qk];
                        unsigned p = atomicAdd(&s.cnt2, 1u);
                        if (p < CAP2)
                            s.cand2[p] = make_uint2(__float_as_uint(pv),
                                                    (unsigned)((q0 + qk) * NC + ck));
                    }
                }
            }
        }
    }
}

__device__ void collect80_approx(Smem& s, unsigned thbits, int tid, int q0) {
    for (int q = tid; q < HQ; q += NT) {
        unsigned u = __float_as_uint(s.last[q]);   // approx == precise for c=80
        bool pass = (u >= thbits);
        unsigned p = ballot_append(&s.cnt, pass);
        if (pass && p < CAP)
            s.cand[p] = make_uint2(u, (unsigned)((q0 + q) * NC + 80));
    }
}

__device__ void collect80_precise(Smem& s, unsigned thbits, int tid, int q0) {
    for (int q = tid; q < HQ; q += NT) {
        unsigned u = __float_as_uint(s.last[q]);
        if (u >= thbits) {
            unsigned p = atomicAdd(&s.cnt2, 1u);
            if (p < CAP2)
                s.cand2[p] = make_uint2(u, (unsigned)((q0 + q) * NC + 80));
        }
    }
}

// K1: each half-block (batch b, rows [h*500,(h+1)*500)) produces its exact
// top-100 (score-bits, flat-idx) into ws[blk*100 .. blk*100+99], rank-ordered.
// Union of the two half-top-100s provably contains the global top-100.
__global__ __launch_bounds__(NT, 4) void half_topk_kernel(
    const float* __restrict__ logits,   // [B, Q, C]
    const float* __restrict__ obj,      // [B, Q]
    const float* __restrict__ unk,      // [B, Q]
    uint2* __restrict__ ws)             // [B*2, 100]
{
    __shared__ Smem s;
    const int blk = blockIdx.x;
    const int b   = blk >> 1;
    const int h   = blk & 1;
    const int q0  = h * HQ;
    const int tid = threadIdx.x;
    const float*  lgf = logits + (size_t)b * QC;
    const float4* lg4 = (const float4*)(lgf + h * HQC);
    uint2* wsb = ws + (size_t)blk * TOPK;

    // ---- init ----
    ((uint4*)s.hist)[tid]      = make_uint4(0u, 0u, 0u, 0u);
    ((uint4*)s.hist)[tid + NT] = make_uint4(0u, 0u, 0u, 0u);
    if (tid == 0) { s.cnt = 0; s.cnt2 = 0; }
    if (tid < TOPK) wsb[tid] = make_uint2(0u, 0u);   // underfill guard (m>=100
                                                     // proven for real data;
                                                     // defined output otherwise)
    for (int q = tid; q < HQ; q += NT) {
        float opv = expf(-obj[b * NQ + q0 + q]);
        float un  = sigmoidf(unk[b * NQ + q0 + q]);
        float om  = 1.f - un;
        s.op[q] = opv; s.omun[q] = om; s.P[q] = opv * om; s.last[q] = opv * un;
    }
    __syncthreads();

    // row bounds + class-80 histogram (no logit reads needed).
    // Half boundary is chunk-aligned -> Pm2 never needs the other half's P.
    for (int q = tid; q < HQ; q += NT) {
        float pm = s.P[q];
        if (q + 1 < HQ) pm = fmaxf(pm, s.P[q + 1]);
        s.Pm2[q] = pm;
        atomicAdd(&s.hist[__float_as_uint(s.last[q]) >> 19], 1u);
    }

    // provisional threshold from class-80 alone (lower bound on final tF).
    unsigned t0   = scan_threshold(s, tid);
    unsigned th0m = t0 ? ((t0 << 19) - MARGIN) : 0;   // bin floor minus sliver

    // ---- single fused walk: histogram + approx-candidate append ----
    build_rows(s, th0m, tid);
    scan_fused(s, lg4, th0m, tid, q0);
    collect80_approx(s, th0m, tid, q0);
    __syncthreads();

    // Final threshold. Bins >= t0 are complete; scan returns tF >= t0.
    unsigned tF   = scan_threshold(s, tid);
    unsigned thCm = tF ? ((tF << 19) - MARGIN) : 0;

    unsigned total = s.cnt;
    if (total <= CAP) {
        // compact from LDS; precise rescore of survivors (L2-hot reload).
        for (int i = tid; i < (int)total; i += NT) {
            uint2 cd = s.cand[i];
            bool pass = (cd.x >= thCm);
            unsigned pvb = 0;
            if (pass) {
                unsigned qg = cd.y / NC;
                unsigned c  = cd.y - qg * NC;
                int ql = (int)qg - q0;
                float pv;
                if (c == 80) pv = s.last[ql];
                else         pv = (s.op[ql] * sigmoidf(lgf[cd.y])) * s.omun[ql];
                pvb = __float_as_uint(pv);
            }
            unsigned p = ballot_append(&s.cnt2, pass);
            if (pass && p < CAP2) s.cand2[p] = make_uint2(pvb, cd.y);
        }
        __syncthreads();
    }
    if (total > CAP || s.cnt2 > CAP2) {
        // rare fallback: precise re-collect by walk at thCm (rowlist built at
        // th0m <= thCm is a superset — still valid).
        __syncthreads();
        if (tid == 0) s.cnt2 = 0;
        __syncthreads();
        collect_precise(s, lg4, thCm, tid, q0);
        collect80_precise(s, thCm, tid, q0);
        __syncthreads();
        if (s.cnt2 > CAP2) {                 // massive-tie pathology only
            __syncthreads();
            if (tid == 0) s.cnt2 = 0;
            __syncthreads();
            collect_precise(s, lg4, tF << 19, tid, q0);
            collect80_precise(s, tF << 19, tid, q0);
            __syncthreads();
        }
    }

    const int m = (int)min(s.cnt2, (unsigned)CAP2);

    // ---- rank within half (exact; scores >= 0 so uint bit order == value
    //      order; tie-break lower flat index first, like lax.top_k) ----
    for (int i = tid; i < m; i += NT) {
        uint2 ci = s.cand2[i];
        int r = 0;
        for (int j = 0; j < m; ++j) {
            uint2 cj = s.cand2[j];      // uniform j -> LDS broadcast
            r += (cj.x > ci.x) || (cj.x == ci.x && cj.y < ci.y);
        }
        if (r < TOPK) wsb[r] = ci;
    }
}

// K2: merge the two half-top-100s per batch, gather boxes, write outputs.
__global__ __launch_bounds__(NT2) void merge_kernel(
    const uint2* __restrict__ ws,       // [B*2, 100]
    const float* __restrict__ boxes,    // [B, Q, 4] cx cy w h
    const float* __restrict__ tsz,      // [B, 2]  (h, w)
    float* __restrict__ out)            // scores[B*K] | labels[B*K] | boxes[B*K*4]
{
    __shared__ uint2 c2[2 * TOPK];
    const int b   = blockIdx.x;
    const int tid = threadIdx.x;
    if (tid < 2 * TOPK) c2[tid] = ws[(size_t)b * 2 * TOPK + tid];
    __syncthreads();
    if (tid < 2 * TOPK) {
        uint2 ci = c2[tid];
        int r = 0;
        for (int j = 0; j < 2 * TOPK; ++j) {
            uint2 cj = c2[j];
            r += (cj.x > ci.x) || (cj.x == ci.x && cj.y < ci.y);
        }
        if (r < TOPK) {
            const float* bx = boxes + (size_t)b * NQ * 4;
            const float img_h = tsz[b * 2 + 0];
            const float img_w = tsz[b * 2 + 1];
            float* o_sc = out + (size_t)b * TOPK;
            float* o_lb = out + (size_t)BATCH * TOPK + (size_t)b * TOPK;
            float* o_bx = out + (size_t)2 * BATCH * TOPK + (size_t)b * TOPK * 4;
            int ei = (int)ci.y;
            o_sc[r] = __uint_as_float(ci.x);
            o_lb[r] = (float)(ei % NC);
            int q = ei / NC;
            float cx = bx[q * 4 + 0];
            float cy = bx[q * 4 + 1];
            float w  = bx[q * 4 + 2];
            float hh = bx[q * 4 + 3];
            o_bx[r * 4 + 0] = (cx - 0.5f * w)  * img_w;
            o_bx[r * 4 + 1] = (cy - 0.5f * hh) * img_h;
            o_bx[r * 4 + 2] = (cx + 0.5f * w)  * img_w;
            o_bx[r * 4 + 3] = (cy + 0.5f * hh) * img_h;
        }
    }
}

extern "C" void kernel_launch(void* const* d_in, const int* in_sizes, int n_in,
                              void* d_out, int out_size, void* d_ws, size_t ws_size,
                              hipStream_t stream) {
    const float* pred_logits = (const float*)d_in[0];
    const float* pred_obj    = (const float*)d_in[1];
    const float* pred_boxes  = (const float*)d_in[2];
    const float* pred_unk    = (const float*)d_in[3];
    const float* target_sz   = (const float*)d_in[4];
    float* out = (float*)d_out;
    uint2* ws  = (uint2*)d_ws;          // uses 512*100*8 = 409,600 B
                                        // (d_ws is >=331 MB per the poison fill)

    half_topk_kernel<<<BATCH * 2, NT, 0, stream>>>(
        pred_logits, pred_obj, pred_unk, ws);
    merge_kernel<<<BATCH, NT2, 0, stream>>>(
        ws, pred_boxes, target_sz, out);
}

// Round 5
// 136.784 us; speedup vs baseline: 1.0988x; 1.0988x over previous
//
#include <hip/hip_runtime.h>
#include <math.h>

#define BATCH  256
#define NQ     1000
#define NC     81
#define QC     81000
#define TOPK   100
#define NBINS  4096
#define CAP    6144
#define CAP2   1024
#define NT     1024
#define MARGIN 4096u   // bit-space sliver below a bin floor (~5e-4 rel) covering
                       // fast-vs-precise score error (~few*1e-6) with 100x slack

// Precise logistic, matching jax.nn.sigmoid (per-q factors + final candidates
// -> output scores bit-identical to the known-absmax=0 kernel).
__device__ __forceinline__ float sigmoidf(float x) {
    if (x >= 0.f) return 1.f / (1.f + expf(-x));
    float e = expf(x);
    return e / (1.f + e);
}

// Fast branch-free logistic (<=1 always; key = P*fast_sig <= P).
__device__ __forceinline__ float fast_sig(float x) {
    return __builtin_amdgcn_rcpf(1.f + __expf(-x));
}

// Wave-aggregated slot reservation: one LDS atomic per wave instead of one per
// passing lane. Return value is only meaningful for lanes with pass==true.
// Safe under divergence: inactive lanes simply don't join the ballot.
__device__ __forceinline__ unsigned ballot_append(unsigned* cnt, bool pass) {
    unsigned long long mask = __ballot(pass);
    unsigned base = 0;
    if (mask) {
        int lane   = (int)(threadIdx.x & 63);
        int leader = __ffsll((long long)mask) - 1;
        if (lane == leader) base = atomicAdd(cnt, (unsigned)__popcll(mask));
        base = __shfl(base, leader, 64);
        base += (unsigned)__popcll(mask & ((1ull << lane) - 1ull));
    }
    return base;
}

struct alignas(16) Smem {     // alignas: hist is zeroed via uint4 (ds_write_b128)
    float    P[NQ];       // exp(-obj)*(1-sig(unk))  — per-row upper bound
    float    op[NQ];      // exp(-obj)               (precise)
    float    omun[NQ];    // 1 - sig(unk)            (precise)
    float    last[NQ];    // exp(-obj)*sig(unk)      class 80 (precise)
    unsigned hist[NBINS];
    uint2    cand[CAP];   // .x = approx key bits, .y = flat index
    uint2    cand2[CAP2]; // .x = precise score bits, .y = flat index
    int      rowlist[NQ];
    unsigned nrows;
    unsigned cnt;
    unsigned cnt2;
    unsigned thr;
};
// ~88 KB LDS; grid 256 = #CUs -> 1 block/CU either way, so size is free.

// Largest bin t with |{keys in bins >= t}| >= TOPK. Wave-0 shuffle suffix scan.
__device__ unsigned scan_threshold(Smem& s, int tid) {
    __syncthreads();
    if (tid < 64) {
        unsigned c = 0;
        #pragma unroll
        for (int j = 0; j < 64; ++j) {
            int jj = (j + tid) & 63;
            c += s.hist[tid * 64 + jj];
        }
        unsigned ssum = c;
        #pragma unroll
        for (int off = 1; off < 64; off <<= 1) {
            unsigned o = __shfl_down(ssum, off, 64);
            if (tid + off < 64) ssum += o;
        }
        unsigned long long bal = __ballot(ssum >= TOPK);
        int cb = 63 - __clzll(bal);
        unsigned tb = 0;
        if (cb >= 0) {
            unsigned S_cb = __shfl(ssum, cb, 64);
            unsigned c_cb = __shfl(c, cb, 64);
            unsigned acc  = S_cb - c_cb;          // count strictly above coarse bin
            unsigned fs = s.hist[cb * 64 + tid];
            #pragma unroll
            for (int off = 1; off < 64; off <<= 1) {
                unsigned o = __shfl_down(fs, off, 64);
                if (tid + off < 64) fs += o;
            }
            unsigned long long bal2 = __ballot(acc + fs >= TOPK);
            int fb = 63 - __clzll(bal2);
            tb = (unsigned)(cb * 64 + fb);
        }
        if (tid == 0) s.thr = tb;
    }
    __syncthreads();
    return s.thr;
}

// Chunk decode for the owned-chunk walk: row q owns float4 chunks
// [ceil(81q/4), ceil(81(q+1)/4)) — disjoint & complete over the batch.
__device__ __forceinline__ void prep_chunk(Smem& s, int id, int& qo, int& e0o,
                                           int& i4o, bool& ok) {
    int r  = id / 21;
    int j  = id - r * 21;
    qo  = s.rowlist[r];
    e0o = NC * qo;
    int t4 = ((e0o + 3) >> 2) + j;
    ok  = (4 * t4 < e0o + NC);
    i4o = ok ? t4 : 0;             // clamp: never load past the batch
}

// FUSED walk over owned chunks of listed rows, 2-deep software pipeline:
// the float4 for iteration i+NT is issued before iteration i is processed,
// overlapping HBM latency with the exp/append work.
__device__ void scan_fused(Smem& s, const float4* __restrict__ lg4,
                           unsigned thbits, int tid) {
    const int total = (int)s.nrows * 21;
    int  qc = 0, e0c = 0, i4c = 0; bool okc = false;
    float4 vc = make_float4(0.f, 0.f, 0.f, 0.f);
    if (tid < total) {
        prep_chunk(s, tid, qc, e0c, i4c, okc);
        if (okc) vc = lg4[i4c];
    }
    for (int idx = tid; idx < total; idx += NT) {
        int  qn = 0, e0n = 0, i4n = 0; bool okn = false;
        float4 vn = make_float4(0.f, 0.f, 0.f, 0.f);
        int idxn = idx + NT;
        if (idxn < total) {
            prep_chunk(s, idxn, qn, e0n, i4n, okn);
            if (okn) vn = lg4[i4n];               // in flight during processing
        }
        if (okc) {
            int c = 4 * i4c - e0c;
            float xs[4] = {vc.x, vc.y, vc.z, vc.w};
            #pragma unroll
            for (int k = 0; k < 4; ++k) {
                int ck = c + k, qk = qc;
                if (ck >= NC) { ck -= NC; ++qk; }
                bool pass = false; unsigned u = 0;
                if (ck < 60) {                   // 60..79 invalid; 80 separate
                    float Pq = s.P[qk];
                    if (__float_as_uint(Pq) >= thbits) {  // element-level bound
                        u = __float_as_uint(Pq * fast_sig(xs[k]));
                        pass = (u >= thbits);
                    }
                }
                if (pass) atomicAdd(&s.hist[u >> 19], 1u);
                unsigned p = ballot_append(&s.cnt, pass);
                if (pass && p < CAP)
                    s.cand[p] = make_uint2(u, (unsigned)(qk * NC + ck));
            }
        }
        qc = qn; e0c = e0n; i4c = i4n; okc = okn; vc = vn;
    }
}

// Fallback: precise collection into cand2 by row walk (rare path).
__device__ void collect_precise(Smem& s, const float4* __restrict__ lg4,
                                unsigned thbits, int tid) {
    const int total = (int)s.nrows * 21;
    for (int idx = tid; idx < total; idx += NT) {
        int q, e0, i4; bool ok;
        prep_chunk(s, idx, q, e0, i4, ok);
        if (ok) {
            float4 v4 = lg4[i4];
            int c = 4 * i4 - e0;
            float xs[4] = {v4.x, v4.y, v4.z, v4.w};
            #pragma unroll
            for (int k = 0; k < 4; ++k) {
                int ck = c + k, qk = q;
                if (ck >= NC) { ck -= NC; ++qk; }
                if (ck < 60) {
                    unsigned u = __float_as_uint(s.P[qk] * fast_sig(xs[k]));
                    if (u >= thbits) {
                        float pv = (s.op[qk] * sigmoidf(xs[k])) * s.omun[qk];
                        unsigned p = atomicAdd(&s.cnt2, 1u);
                        if (p < CAP2)
                            s.cand2[p] = make_uint2(__float_as_uint(pv),
                                                    (unsigned)(qk * NC + ck));
                    }
                }
            }
        }
    }
}

__device__ void collect80_precise(Smem& s, unsigned thbits, int tid) {
    for (int q = tid; q < NQ; q += NT) {
        unsigned u = __float_as_uint(s.last[q]);
        if (u >= thbits) {
            unsigned p = atomicAdd(&s.cnt2, 1u);
            if (p < CAP2) s.cand2[p] = make_uint2(u, (unsigned)(q * NC + 80));
        }
    }
}

__global__ __launch_bounds__(NT) void postprocess_kernel(
    const float* __restrict__ logits,   // [B, Q, C]
    const float* __restrict__ obj,      // [B, Q]
    const float* __restrict__ boxes,    // [B, Q, 4] cx cy w h
    const float* __restrict__ unk,      // [B, Q]
    const float* __restrict__ tsz,      // [B, 2]  (h, w)
    float* __restrict__ out)            // scores[B*K] | labels[B*K] | boxes[B*K*4]
{
    __shared__ Smem s;
    const int b   = blockIdx.x;
    const int tid = threadIdx.x;
    const float*  lgf = logits + (size_t)b * QC;
    const float4* lg4 = (const float4*)lgf;

    // ---- phase A: zero hist + per-row factors (one row per thread) ----
    *(uint4*)&s.hist[tid * 4] = make_uint4(0u, 0u, 0u, 0u);
    if (tid == 0) { s.nrows = 0; s.cnt = 0; s.cnt2 = 0; }
    float Pmine = 0.f; unsigned lastbits = 0;
    if (tid < NQ) {
        float opv = expf(-obj[b * NQ + tid]);
        float un  = sigmoidf(unk[b * NQ + tid]);
        float om  = 1.f - un;
        float la  = opv * un;
        Pmine     = opv * om;
        lastbits  = __float_as_uint(la);
        s.op[tid] = opv; s.omun[tid] = om; s.P[tid] = Pmine; s.last[tid] = la;
    }
    __syncthreads();   // hist zero + P[] visible

    // ---- phase B: pair-max bound (register) + class-80 histogram ----
    float pm2 = Pmine;
    if (tid < NQ) {
        if (tid + 1 < NQ) pm2 = fmaxf(pm2, s.P[tid + 1]);
        atomicAdd(&s.hist[lastbits >> 19], 1u);
    }

    // provisional threshold from class-80 alone (lower bound on final tF).
    // scan_threshold's entry barrier orders the hist atomics above.
    unsigned t0   = scan_threshold(s, tid);
    unsigned th0m = t0 ? ((t0 << 19) - MARGIN) : 0;   // bin floor minus sliver

    // ---- phase C: row-list build + class-80 candidate collect (one pass) ----
    {
        bool pr = (tid < NQ) && (__float_as_uint(pm2) >= th0m);
        unsigned p = ballot_append(&s.nrows, pr);
        if (pr) s.rowlist[p] = tid;
        bool p80 = (tid < NQ) && (lastbits >= th0m);   // approx==precise for c=80
        unsigned p2 = ballot_append(&s.cnt, p80);
        if (p80 && p2 < CAP)
            s.cand[p2] = make_uint2(lastbits, (unsigned)(tid * NC + 80));
    }
    __syncthreads();   // rowlist/nrows visible

    // ---- phase D: fused walk: histogram + approx-candidate append ----
    scan_fused(s, lg4, th0m, tid);

    // Final threshold. Bins >= t0 are complete (sliver counts land in bin
    // t0-1 and below); cum(t0) >= TOPK already, so the scan returns tF >= t0.
    // scan_threshold's entry barrier orders phase D's writes.
    unsigned tF   = scan_threshold(s, tid);
    unsigned thCm = tF ? ((tF << 19) - MARGIN) : 0;

    unsigned total = s.cnt;
    if (total <= CAP) {
        // ---- phase E: compact from LDS; precise rescore (L2-hot reload).
        // Any true top-100 element has approx key >= binfloor(tF)*(1-4e-5),
        // i.e. bits >= thCm -> provable superset.
        for (int i = tid; i < (int)total; i += NT) {
            uint2 cd = s.cand[i];
            bool pass = (cd.x >= thCm);
            unsigned pvb = 0;
            if (pass) {
                unsigned q = cd.y / NC;
                unsigned c = cd.y - q * NC;
                float pv;
                if (c == 80) pv = s.last[q];
                else         pv = (s.op[q] * sigmoidf(lgf[cd.y])) * s.omun[q];
                pvb = __float_as_uint(pv);
            }
            unsigned p = ballot_append(&s.cnt2, pass);
            if (pass && p < CAP2) s.cand2[p] = make_uint2(pvb, cd.y);
        }
        __syncthreads();
    }
    if (total > CAP || s.cnt2 > CAP2) {
        // rare fallback: precise re-collect by walk at thCm (rowlist built at
        // th0m <= thCm is a superset — still valid).
        __syncthreads();
        if (tid == 0) s.cnt2 = 0;
        __syncthreads();
        collect_precise(s, lg4, thCm, tid);
        collect80_precise(s, thCm, tid);
        __syncthreads();
        if (s.cnt2 > CAP2) {                 // massive-tie pathology only
            __syncthreads();
            if (tid == 0) s.cnt2 = 0;
            __syncthreads();
            collect_precise(s, lg4, tF << 19, tid);
            collect80_precise(s, tF << 19, tid);
            __syncthreads();
        }
    }

    const int m = (int)min(s.cnt2, (unsigned)CAP2);

    // ---- rank (exact; scores >= 0 so uint bit order == value order;
    //      tie-break lower flat index first, like lax.top_k) ----
    const float4* bx4 = (const float4*)(boxes + (size_t)b * NQ * 4);
    const float img_h = tsz[b * 2 + 0];
    const float img_w = tsz[b * 2 + 1];
    float* o_sc = out + (size_t)b * TOPK;
    float* o_lb = out + (size_t)BATCH * TOPK + (size_t)b * TOPK;
    float* o_bx = out + (size_t)2 * BATCH * TOPK + (size_t)b * TOPK * 4;

    for (int i = tid; i < m; i += NT) {
        uint2 ci = s.cand2[i];
        int r = 0;
        for (int j = 0; j < m; ++j) {
            uint2 cj = s.cand2[j];      // uniform j -> LDS broadcast, no conflict
            r += (cj.x > ci.x) || (cj.x == ci.x && cj.y < ci.y);
        }
        if (r < TOPK) {
            int ei = (int)ci.y;
            o_sc[r] = __uint_as_float(ci.x);
            o_lb[r] = (float)(ei % NC);
            int q = ei / NC;
            float4 bb = bx4[q];                    // cx cy w h in one load
            o_bx[r * 4 + 0] = (bb.x - 0.5f * bb.z) * img_w;
            o_bx[r * 4 + 1] = (bb.y - 0.5f * bb.w) * img_h;
            o_bx[r * 4 + 2] = (bb.x + 0.5f * bb.z) * img_w;
            o_bx[r * 4 + 3] = (bb.y + 0.5f * bb.w) * img_h;
        }
    }
}

extern "C" void kernel_launch(void* const* d_in, const int* in_sizes, int n_in,
                              void* d_out, int out_size, void* d_ws, size_t ws_size,
                              hipStream_t stream) {
    const float* pred_logits = (const float*)d_in[0];
    const float* pred_obj    = (const float*)d_in[1];
    const float* pred_boxes  = (const float*)d_in[2];
    const float* pred_unk    = (const float*)d_in[3];
    const float* target_sz   = (const float*)d_in[4];
    float* out = (float*)d_out;
    postprocess_kernel<<<BATCH, NT, 0, stream>>>(
        pred_logits, pred_obj, pred_boxes, pred_unk, target_sz, out);
}